// Round 12
// baseline (182.502 us; speedup 1.0000x reference)
//
#include <hip/hip_runtime.h>

#define MM 128
#define NN 128
#define KK 128
#define NB 2                    // batches in flight per block (4 total -> 2 block-waves)
#define ITERS 8
#define WIN 10
#define PRS 24                  // k-pair stride (dwords): 12 q-slots x 2
#define QS 2                    // q stride (dwords) in pair-interleaved layout
#define PLANE 120               // 5 k-pairs x 24 dwords per wp-plane
#define BUFSZ (WIN * PLANE)     // 1200 floats per window buffer
#define MNK (MM * NN * KK)

typedef float v2f __attribute__((ext_vector_type(2)));

// Wave-64 sum via DPP adds (no DS-pipe traffic, short dep chain).
// Result valid in LANE 63 only.
__device__ __forceinline__ float wave_sum63(float v) {
  v += __int_as_float(__builtin_amdgcn_update_dpp(
      0, __float_as_int(v), 0x111, 0xF, 0xF, true));  // row_shr:1
  v += __int_as_float(__builtin_amdgcn_update_dpp(
      0, __float_as_int(v), 0x112, 0xF, 0xF, true));  // row_shr:2
  v += __int_as_float(__builtin_amdgcn_update_dpp(
      0, __float_as_int(v), 0x114, 0xF, 0xF, true));  // row_shr:4
  v += __int_as_float(__builtin_amdgcn_update_dpp(
      0, __float_as_int(v), 0x118, 0xF, 0xF, true));  // row_shr:8
  v += __int_as_float(__builtin_amdgcn_update_dpp(
      0, __float_as_int(v), 0x142, 0xF, 0xF, true));  // row_bcast:15
  v += __int_as_float(__builtin_amdgcn_update_dpp(
      0, __float_as_int(v), 0x143, 0xF, 0xF, true));  // row_bcast:31
  return v;
}

// Force a block-uniform value into an SGPR (frees VGPR pressure).
__device__ __forceinline__ float bcast_first(float v) {
  return __uint_as_float(__builtin_amdgcn_readfirstlane(__float_as_uint(v)));
}

// Pin values as opaque registers (non-rematerializable; R8 win: stops the
// compiler from re-loading weights from global every iteration).
__device__ __forceinline__ void pin(float& v) { asm("" : "+v"(v)); }
__device__ __forceinline__ void pin2(v2f& v) { asm("" : "+v"(v)); }

// Packed dual-FP32 FMA (gfx90a+): d = a*b + d elementwise on 2 lanes.
__device__ __forceinline__ void pk_fma(v2f& d, v2f a, v2f b) {
  asm("v_pk_fma_f32 %0, %1, %2, %0" : "+v"(d) : "v"(a), "v"(b));
}

// R12 CHANGE (occupancy via batch-split): R11 sat at 3.5 waves/SIMD (43.6%),
// register-bound (~60 pinned + ~30 arch + 4-batch state), with no pipe >45%
// busy -> overlap deficit, not a pipe roofline. Split the 4 batches across
// 2x blocks: grid 8192, each block runs NB=2 batches. Per-thread state drops
// to ~90 combined regs -> 5 waves/SIMD fit. LDS is PADDED (red[2960]) to
// ~31KB so the allocator's LDS-derived occupancy target is 5 blocks/CU ->
// budget 102 regs -> no spill (R5-R7 lesson: the target comes from LDS, and
// attributes don't override it). Weights/x are re-read by the second
// batch-pair: L3-served (216MB < 256MB), same XCD (d vs d+4096 -> same d&7).
//
// Retained: (1,1,2) micro-tile, 27 float2 weight pairs pinned, pair-
// interleaved window layout (ONE ds_read2_b64 per tap-row, conflict-free),
// ping-pong buffers (ONE barrier/iter), DPP reductions, XCD swizzle.
__global__ __launch_bounds__(256, 4) void gridnet_kernel(
    const float* __restrict__ weight, const float* __restrict__ bias,
    const float* __restrict__ rscale, const float* __restrict__ x,
    float* __restrict__ out) {
  __shared__ __align__(16) float Wl[NB][2][BUFSZ];   // 19200 B
  __shared__ float red[2960];  // [0,64): staging; [64,96)/[96,128): iter banks;
                               // tail = deliberate pad -> LDS ~31KB -> 5 blocks/CU

  const int t = threadIdx.x;
  const int r0 = (t & 3) * 2, q = (t >> 2) & 7, p = t >> 5;
  const int wv = t >> 6;

  // batch-pair major; XCD swizzle on the spatial index (FETCH 575->139MB).
  const int d = blockIdx.x;
  const int bp = d >> 12;              // 0: batches 0,1; 1: batches 2,3
  const int ds = d & 4095;
  const int sp = (ds & 7) * 512 + (ds >> 3);
  const int bm = sp >> 8, bn = (sp >> 4) & 15, bk = sp & 15;

  const int gm0 = bm * 8, gn0 = bn * 8, gk0 = bk * 8;
  const int g = ((gm0 + p) * NN + (gn0 + q)) * KK + (gk0 + r0);

  // per-thread weights, packed by tap-row: row = i*3 + jj (9 rows), with
  // Pa[row] = pair at k-tap 0, Pm[row] = k-tap 1, Pc[row] = k-tap 2.
  v2f Pa[9], Pm[9], Pc[9];
  float S0 = 0.f, S1 = 0.f;
#pragma unroll
  for (int row = 0; row < 9; ++row) {
    const int o = row * 3;
    v2f wa = *(const v2f*)(weight + (o + 0) * MNK + g);
    v2f wm = *(const v2f*)(weight + (o + 1) * MNK + g);
    v2f wc = *(const v2f*)(weight + (o + 2) * MNK + g);
    Pa[row] = wa; Pm[row] = wm; Pc[row] = wc;
    S0 += wa.x + wm.x + wc.x;
    S1 += wa.y + wm.y + wc.y;
  }
  float2 bv = *(const float2*)(bias + g);
  float2 rv = *(const float2*)(rscale + g);
#pragma unroll
  for (int row = 0; row < 9; ++row) { pin2(Pa[row]); pin2(Pm[row]); pin2(Pc[row]); }
  pin(S0); pin(S1);
  pin(bv.x); pin(bv.y); pin(rv.x); pin(rv.y);

  // pair-interleaved window coords: L(wp,wq,wk) = wp*120 + (wk>>1)*24 + wq*2 + (wk&1)
  const int cb = p * PLANE + (r0 >> 1) * PRS + q * QS;      // (i=0,jj=0) tap base
  const int wb1 = (p + 1) * PLANE + (r0 >> 1) * PRS + (q + 1) * QS + 1;  // cell dr=0
  const int wb2 = wb1 + PRS - 1;                                          // cell dr=1

  // ---- stage NB batch windows into buf0; halo mirrored into buf1 ----
  float sA[NB] = {0.f, 0.f}, sAq[NB] = {0.f, 0.f};
  float sH[NB] = {0.f, 0.f}, sHq[NB] = {0.f, 0.f};
  for (int idx = t; idx < 1000; idx += 256) {
    int wp_ = idx / 100;
    int rem = idx - wp_ * 100;
    int wq = rem / 10;
    int wk = rem - wq * 10;
    int gm = gm0 - 1 + wp_, gn = gn0 - 1 + wq, gk = gk0 - 1 + wk;
    const bool inb = (unsigned)gm < 128u && (unsigned)gn < 128u && (unsigned)gk < 128u;
    const bool halo = (wp_ == 0 || wp_ == 9 || wq == 0 || wq == 9 || wk == 0 || wk == 9);
    const int gx = (gm * NN + gn) * KK + gk;        // only used when inb
    const int li = wp_ * PLANE + (wk >> 1) * PRS + wq * QS + (wk & 1);
#pragma unroll
    for (int b = 0; b < NB; ++b) {
      float v = 0.f;
      if (inb) v = x[(bp * NB + b) * MNK + gx];
      Wl[b][0][li] = v;
      sA[b] += v; sAq[b] += v * v;
      if (halo) { Wl[b][1][li] = v; sH[b] += v; sHq[b] += v * v; }
    }
  }
#pragma unroll
  for (int b = 0; b < NB; ++b) {
    sA[b] = wave_sum63(sA[b]);  sAq[b] = wave_sum63(sAq[b]);
    sH[b] = wave_sum63(sH[b]);  sHq[b] = wave_sum63(sHq[b]);
  }
  if ((t & 63) == 63) {
#pragma unroll
    for (int b = 0; b < NB; ++b) {
      float4 pk; pk.x = sA[b]; pk.y = sAq[b]; pk.z = sH[b]; pk.w = sHq[b];
      *(float4*)&red[(wv * NB + b) * 4] = pk;
    }
  }
  __syncthreads();

  float invv[NB], imv[NB], hS[NB], hQ[NB];  // block-uniform -> SGPRs
#pragma unroll
  for (int b = 0; b < NB; ++b) {
    float tS = 0.f, tQ = 0.f, hs = 0.f, hq = 0.f;
#pragma unroll
    for (int i = 0; i < 4; ++i) {
      float4 pk = *(const float4*)&red[(i * NB + b) * 4];  // broadcast read
      tS += pk.x; tQ += pk.y; hs += pk.z; hq += pk.w;
    }
    hS[b] = bcast_first(hs); hQ[b] = bcast_first(hq);
    float mu = tS * (1.0f / 1000.0f);
    float var = tQ * (1.0f / 1000.0f) - mu * mu;
    float inv = __builtin_amdgcn_rsqf(var + 1e-5f);
    invv[b] = bcast_first(inv); imv[b] = bcast_first(inv * mu);
  }
  float a[NB][2];
#pragma unroll
  for (int b = 0; b < NB; ++b) {
    a[b][0] = Wl[b][0][wb1];
    a[b][1] = Wl[b][0][wb2];
  }

#pragma unroll 2
  for (int it = 0; it < ITERS; ++it) {
    const int cur = it & 1;
    // ---- 3^3 locally-connected conv + silu, NB batches, from buf[cur] ----
    // (normalization folded: z = bias + inv*conv_raw - inv*mu*S)
#pragma unroll
    for (int b = 0; b < NB; ++b) {
      const float* __restrict__ cp = &Wl[b][cur][cb];
      v2f accp = {0.f, 0.f};
#pragma unroll
      for (int i = 0; i < 3; ++i)
#pragma unroll
        for (int jj = 0; jj < 3; ++jj) {
          const int row = i * 3 + jj;
          const float* rp = cp + i * PLANE + jj * QS;
          v2f U01 = *(const v2f*)rp;          // {u0,u1}: one half of ds_read2_b64
          v2f U23 = *(const v2f*)(rp + PRS);  // {u2,u3}: other half (off +96B)
          pk_fma(accp, Pa[row], U01);   // acc0 += wa0*u0 ; acc1 += wa1*u1
          pk_fma(accp, Pc[row], U23);   // acc0 += wc0*u2 ; acc1 += wc1*u3
          accp.x += Pm[row].x * U01.y;  // acc0 += wm0*u1
          accp.y += Pm[row].y * U23.x;  // acc1 += wm1*u2
        }
      float z0 = bv.x + invv[b] * accp.x - imv[b] * S0;
      float z1 = bv.y + invv[b] * accp.y - imv[b] * S1;
      float sg0 = __builtin_amdgcn_rcpf(1.0f + __expf(-z0));
      float sg1 = __builtin_amdgcn_rcpf(1.0f + __expf(-z1));
      a[b][0] += rv.x * (z0 * sg0);
      a[b][1] += rv.y * (z1 * sg1);
    }
    if (it == ITERS - 1) break;
    // ---- write new interiors into buf[cur^1] (WAR-safe: buf[cur^1] readers
    // finished before the barrier at the end of the previous iteration) ----
    float ls[NB], lq[NB];
#pragma unroll
    for (int b = 0; b < NB; ++b) {
      Wl[b][cur ^ 1][wb1] = a[b][0];
      Wl[b][cur ^ 1][wb2] = a[b][1];
      ls[b] = wave_sum63(a[b][0] + a[b][1]);
      lq[b] = wave_sum63(a[b][0] * a[b][0] + a[b][1] * a[b][1]);
    }
    const int bank = 64 + cur * 32;  // alternate banks: single-barrier race-free
    if ((t & 63) == 63) {
#pragma unroll
      for (int b = 0; b < NB; ++b) {
        float2 pk; pk.x = ls[b]; pk.y = lq[b];
        *(float2*)&red[bank + (wv * NB + b) * 2] = pk;
      }
    }
    __syncthreads();  // ONE barrier: interiors visible + partials ready
#pragma unroll
    for (int b = 0; b < NB; ++b) {
      float tS = hS[b], tQ = hQ[b];
#pragma unroll
      for (int i = 0; i < 4; ++i) {
        float2 pk = *(const float2*)&red[bank + (i * NB + b) * 2];  // broadcast
        tS += pk.x; tQ += pk.y;
      }
      float mu = tS * (1.0f / 1000.0f);
      float var = tQ * (1.0f / 1000.0f) - mu * mu;
      float inv = __builtin_amdgcn_rsqf(var + 1e-5f);
      invv[b] = bcast_first(inv); imv[b] = bcast_first(inv * mu);
    }
  }
  // ---- final interiors from registers (r0 even -> float2-aligned) ----
#pragma unroll
  for (int b = 0; b < NB; ++b) {
    float2 ov; ov.x = a[b][0]; ov.y = a[b][1];
    *(float2*)(out + (bp * NB + b) * MNK + g) = ov;
  }
}

extern "C" void kernel_launch(void* const* d_in, const int* in_sizes, int n_in,
                              void* d_out, int out_size, void* d_ws, size_t ws_size,
                              hipStream_t stream) {
  const float* weight = (const float*)d_in[0];
  const float* bias   = (const float*)d_in[1];
  const float* rscale = (const float*)d_in[2];
  const float* x      = (const float*)d_in[3];
  // d_in[4] = inner_iterations (8), d_in[5] = block_size (8): fixed by harness
  float* out = (float*)d_out;
  gridnet_kernel<<<dim3(2 * 16 * 16 * 16), dim3(256), 0, stream>>>(
      weight, bias, rscale, x, out);
}

// Round 13
// 167.065 us; speedup vs baseline: 1.0924x; 1.0924x over previous
//
#include <hip/hip_runtime.h>

#define MM 128
#define NN 128
#define KK 128
#define NB 4
#define ITERS 8
#define WIN 10
#define PRS 24                  // k-pair stride (dwords): 12 q-slots x 2
#define QS 2                    // q stride (dwords) in pair-interleaved layout
#define PLANE 120               // 5 k-pairs x 24 dwords per wp-plane
#define BUFSZ (WIN * PLANE)     // 1200 floats per window buffer
#define MNK (MM * NN * KK)

typedef float v2f __attribute__((ext_vector_type(2)));

// Wave-64 sum via DPP adds (no DS-pipe traffic, short dep chain).
// Result valid in LANE 63 only.
__device__ __forceinline__ float wave_sum63(float v) {
  v += __int_as_float(__builtin_amdgcn_update_dpp(
      0, __float_as_int(v), 0x111, 0xF, 0xF, true));  // row_shr:1
  v += __int_as_float(__builtin_amdgcn_update_dpp(
      0, __float_as_int(v), 0x112, 0xF, 0xF, true));  // row_shr:2
  v += __int_as_float(__builtin_amdgcn_update_dpp(
      0, __float_as_int(v), 0x114, 0xF, 0xF, true));  // row_shr:4
  v += __int_as_float(__builtin_amdgcn_update_dpp(
      0, __float_as_int(v), 0x118, 0xF, 0xF, true));  // row_shr:8
  v += __int_as_float(__builtin_amdgcn_update_dpp(
      0, __float_as_int(v), 0x142, 0xF, 0xF, true));  // row_bcast:15
  v += __int_as_float(__builtin_amdgcn_update_dpp(
      0, __float_as_int(v), 0x143, 0xF, 0xF, true));  // row_bcast:31
  return v;
}

// Force a block-uniform value into an SGPR (frees VGPR pressure).
__device__ __forceinline__ float bcast_first(float v) {
  return __uint_as_float(__builtin_amdgcn_readfirstlane(__float_as_uint(v)));
}

// Pin values as opaque registers (non-rematerializable; R8 win: stops the
// compiler from re-loading weights from global every iteration).
__device__ __forceinline__ void pin(float& v) { asm("" : "+v"(v)); }
__device__ __forceinline__ void pin2(v2f& v) { asm("" : "+v"(v)); }

// Packed dual-FP32 FMA (gfx90a+): d = a*b + d elementwise on 2 lanes.
__device__ __forceinline__ void pk_fma(v2f& d, v2f a, v2f b) {
  asm("v_pk_fma_f32 %0, %1, %2, %0" : "+v"(d) : "v"(a), "v"(b));
}

// R13 = R11 base (R12 batch-split regressed: occupancy stayed reg-capped at 4
// waves/SIMD and FETCH doubled to 266MB from weight re-reads) + two
// instruction-count micro-opts:
//  (a) iter-stats partials stored (batch, wave)-major -> per-iter recompute
//      reads 2x ds_read_b128 per batch instead of 4x ds_read_b64
//      (stats reads/thread-iter: 16 -> 8).
//  (b) paired-rcp sigmoid: per batch, r = rcp(d0*d1); sg0 = r*d1; sg1 = r*d0
//      -> transcendental ops/iter 16 -> 12 for +12 cheap muls.
// Retained: (1,1,2) micro-tile, 27 float2 weight pairs pinned, pair-
// interleaved window layout (ONE ds_read2_b64 per tap-row, conflict-free),
// 4 batches in flight, ping-pong buffers (ONE barrier/iter), DPP reductions,
// XCD swizzle, 38.9KB LDS (4 blocks/CU -> 128-reg allocator budget).
__global__ __launch_bounds__(256, 4) void gridnet_kernel(
    const float* __restrict__ weight, const float* __restrict__ bias,
    const float* __restrict__ rscale, const float* __restrict__ x,
    float* __restrict__ out) {
  __shared__ __align__(16) float Wl[NB][2][BUFSZ];   // 38400 B
  __shared__ __align__(16) float red[128];  // [0,64): staging; [64,96)/[96,128): iter banks

  const int t = threadIdx.x;
  const int r0 = (t & 3) * 2, q = (t >> 2) & 7, p = t >> 5;
  const int wv = t >> 6;

  // XCD swizzle: adjacent-bk spatial blocks (sharing 64B weight/x lines) land
  // on the same XCD -> second read hits that XCD's L2. (FETCH 575->139MB.)
  const int d = blockIdx.x;
  const int sp = (d & 7) * 512 + (d >> 3);
  const int bm = sp >> 8, bn = (sp >> 4) & 15, bk = sp & 15;

  const int gm0 = bm * 8, gn0 = bn * 8, gk0 = bk * 8;
  const int g = ((gm0 + p) * NN + (gn0 + q)) * KK + (gk0 + r0);

  // per-thread weights, packed by tap-row: row = i*3 + jj (9 rows), with
  // Pa[row] = pair at k-tap 0, Pm[row] = k-tap 1, Pc[row] = k-tap 2.
  v2f Pa[9], Pm[9], Pc[9];
  float S0 = 0.f, S1 = 0.f;
#pragma unroll
  for (int row = 0; row < 9; ++row) {
    const int o = row * 3;
    v2f wa = *(const v2f*)(weight + (o + 0) * MNK + g);
    v2f wm = *(const v2f*)(weight + (o + 1) * MNK + g);
    v2f wc = *(const v2f*)(weight + (o + 2) * MNK + g);
    Pa[row] = wa; Pm[row] = wm; Pc[row] = wc;
    S0 += wa.x + wm.x + wc.x;
    S1 += wa.y + wm.y + wc.y;
  }
  float2 bv = *(const float2*)(bias + g);
  float2 rv = *(const float2*)(rscale + g);
#pragma unroll
  for (int row = 0; row < 9; ++row) { pin2(Pa[row]); pin2(Pm[row]); pin2(Pc[row]); }
  pin(S0); pin(S1);
  pin(bv.x); pin(bv.y); pin(rv.x); pin(rv.y);

  // pair-interleaved window coords: L(wp,wq,wk) = wp*120 + (wk>>1)*24 + wq*2 + (wk&1)
  const int cb = p * PLANE + (r0 >> 1) * PRS + q * QS;      // (i=0,jj=0) tap base
  const int wb1 = (p + 1) * PLANE + (r0 >> 1) * PRS + (q + 1) * QS + 1;  // cell dr=0
  const int wb2 = wb1 + PRS - 1;                                          // cell dr=1

  // ---- stage all 4 batch windows into buf0; halo mirrored into buf1 ----
  float sA[NB] = {0.f, 0.f, 0.f, 0.f}, sAq[NB] = {0.f, 0.f, 0.f, 0.f};
  float sH[NB] = {0.f, 0.f, 0.f, 0.f}, sHq[NB] = {0.f, 0.f, 0.f, 0.f};
  for (int idx = t; idx < 1000; idx += 256) {
    int wp_ = idx / 100;
    int rem = idx - wp_ * 100;
    int wq = rem / 10;
    int wk = rem - wq * 10;
    int gm = gm0 - 1 + wp_, gn = gn0 - 1 + wq, gk = gk0 - 1 + wk;
    const bool inb = (unsigned)gm < 128u && (unsigned)gn < 128u && (unsigned)gk < 128u;
    const bool halo = (wp_ == 0 || wp_ == 9 || wq == 0 || wq == 9 || wk == 0 || wk == 9);
    const int gx = (gm * NN + gn) * KK + gk;        // only used when inb
    const int li = wp_ * PLANE + (wk >> 1) * PRS + wq * QS + (wk & 1);
#pragma unroll
    for (int b = 0; b < NB; ++b) {
      float v = 0.f;
      if (inb) v = x[b * MNK + gx];
      Wl[b][0][li] = v;
      sA[b] += v; sAq[b] += v * v;
      if (halo) { Wl[b][1][li] = v; sH[b] += v; sHq[b] += v * v; }
    }
  }
#pragma unroll
  for (int b = 0; b < NB; ++b) {
    sA[b] = wave_sum63(sA[b]);  sAq[b] = wave_sum63(sAq[b]);
    sH[b] = wave_sum63(sH[b]);  sHq[b] = wave_sum63(sHq[b]);
  }
  if ((t & 63) == 63) {
#pragma unroll
    for (int b = 0; b < NB; ++b) {
      float4 pk; pk.x = sA[b]; pk.y = sAq[b]; pk.z = sH[b]; pk.w = sHq[b];
      *(float4*)&red[(wv * NB + b) * 4] = pk;
    }
  }
  __syncthreads();

  float invv[NB], imv[NB], hS[NB], hQ[NB];  // block-uniform -> SGPRs
#pragma unroll
  for (int b = 0; b < NB; ++b) {
    float tS = 0.f, tQ = 0.f, hs = 0.f, hq = 0.f;
#pragma unroll
    for (int i = 0; i < 4; ++i) {
      float4 pk = *(const float4*)&red[(i * NB + b) * 4];  // broadcast read
      tS += pk.x; tQ += pk.y; hs += pk.z; hq += pk.w;
    }
    hS[b] = bcast_first(hs); hQ[b] = bcast_first(hq);
    float mu = tS * (1.0f / 1000.0f);
    float var = tQ * (1.0f / 1000.0f) - mu * mu;
    float inv = __builtin_amdgcn_rsqf(var + 1e-5f);
    invv[b] = bcast_first(inv); imv[b] = bcast_first(inv * mu);
  }
  float a[NB][2];
#pragma unroll
  for (int b = 0; b < NB; ++b) {
    a[b][0] = Wl[b][0][wb1];
    a[b][1] = Wl[b][0][wb2];
  }

#pragma unroll 2
  for (int it = 0; it < ITERS; ++it) {
    const int cur = it & 1;
    // ---- 3^3 locally-connected conv + silu, all 4 batches, from buf[cur] ----
    // (normalization folded: z = bias + inv*conv_raw - inv*mu*S)
#pragma unroll
    for (int b = 0; b < NB; ++b) {
      const float* __restrict__ cp = &Wl[b][cur][cb];
      v2f accp = {0.f, 0.f};
#pragma unroll
      for (int i = 0; i < 3; ++i)
#pragma unroll
        for (int jj = 0; jj < 3; ++jj) {
          const int row = i * 3 + jj;
          const float* rp = cp + i * PLANE + jj * QS;
          v2f U01 = *(const v2f*)rp;          // {u0,u1}: one half of ds_read2_b64
          v2f U23 = *(const v2f*)(rp + PRS);  // {u2,u3}: other half (off +96B)
          pk_fma(accp, Pa[row], U01);   // acc0 += wa0*u0 ; acc1 += wa1*u1
          pk_fma(accp, Pc[row], U23);   // acc0 += wc0*u2 ; acc1 += wc1*u3
          accp.x += Pm[row].x * U01.y;  // acc0 += wm0*u1
          accp.y += Pm[row].y * U23.x;  // acc1 += wm1*u2
        }
      float z0 = bv.x + invv[b] * accp.x - imv[b] * S0;
      float z1 = bv.y + invv[b] * accp.y - imv[b] * S1;
      // paired-rcp sigmoid: one rcp serves both cells
      float e0 = __expf(-z0), e1 = __expf(-z1);
      float d0 = 1.0f + e0, d1 = 1.0f + e1;
      float rr = __builtin_amdgcn_rcpf(d0 * d1);
      a[b][0] += rv.x * (z0 * (rr * d1));
      a[b][1] += rv.y * (z1 * (rr * d0));
    }
    if (it == ITERS - 1) break;
    // ---- write new interiors into buf[cur^1] (WAR-safe: buf[cur^1] readers
    // finished before the barrier at the end of the previous iteration) ----
    float ls[NB], lq[NB];
#pragma unroll
    for (int b = 0; b < NB; ++b) {
      Wl[b][cur ^ 1][wb1] = a[b][0];
      Wl[b][cur ^ 1][wb2] = a[b][1];
      ls[b] = wave_sum63(a[b][0] + a[b][1]);
      lq[b] = wave_sum63(a[b][0] * a[b][0] + a[b][1] * a[b][1]);
    }
    const int bank = 64 + cur * 32;  // alternate banks: single-barrier race-free
    if ((t & 63) == 63) {
      // (batch, wave)-major: batch b's 4 wave-partials contiguous (8 dwords)
#pragma unroll
      for (int b = 0; b < NB; ++b) {
        float2 pk; pk.x = ls[b]; pk.y = lq[b];
        *(float2*)&red[bank + b * 8 + wv * 2] = pk;
      }
    }
    __syncthreads();  // ONE barrier: interiors visible + partials ready
#pragma unroll
    for (int b = 0; b < NB; ++b) {
      // 2x b128 broadcast reads grab all 4 wave-partials (was 4x b64)
      float4 pa = *(const float4*)&red[bank + b * 8];
      float4 pb = *(const float4*)&red[bank + b * 8 + 4];
      float tS = hS[b] + pa.x + pa.z + pb.x + pb.z;
      float tQ = hQ[b] + pa.y + pa.w + pb.y + pb.w;
      float mu = tS * (1.0f / 1000.0f);
      float var = tQ * (1.0f / 1000.0f) - mu * mu;
      float inv = __builtin_amdgcn_rsqf(var + 1e-5f);
      invv[b] = bcast_first(inv); imv[b] = bcast_first(inv * mu);
    }
  }
  // ---- final interiors from registers (r0 even -> float2-aligned) ----
#pragma unroll
  for (int b = 0; b < NB; ++b) {
    float2 ov; ov.x = a[b][0]; ov.y = a[b][1];
    *(float2*)(out + b * MNK + g) = ov;
  }
}

extern "C" void kernel_launch(void* const* d_in, const int* in_sizes, int n_in,
                              void* d_out, int out_size, void* d_ws, size_t ws_size,
                              hipStream_t stream) {
  const float* weight = (const float*)d_in[0];
  const float* bias   = (const float*)d_in[1];
  const float* rscale = (const float*)d_in[2];
  const float* x      = (const float*)d_in[3];
  // d_in[4] = inner_iterations (8), d_in[5] = block_size (8): fixed by harness
  float* out = (float*)d_out;
  gridnet_kernel<<<dim3(16 * 16 * 16), dim3(256), 0, stream>>>(
      weight, bias, rscale, x, out);
}